// Round 9
// baseline (425.448 us; speedup 1.0000x reference)
//
#include <hip/hip_runtime.h>
#include <cstddef>

// N=Q=16384, D=3. d_out (flat f32): mask [Q*N] | row_splits [Q+1] | weights [Q*N].
// Weights region starts at abs elem ≡ 1 (mod 4); aligned weights quads cover row
// elems {4k-1..4k+2}. Quad slot 0 = left neighbor's value: shfl_up across lanes,
// direct recompute at lane 0, prev-row tail at row heads.
// R4: all stores dwordx4.  R6: q-loop outermost (best 409.6).  R7: block-split
// regressed.  R8: register prefetch neutral at 8 blocks/CU (kept for R9's low
// occupancy).  R9: QB=64, grid=256 = 1 block/CU -> 512 chip-wide write streams
// (was ~4096), each 4MB contiguous; mimics fillBufferAligned's few-long-streams
// shape (it hits 6.33 TB/s at 11% occupancy).

namespace {

constexpr int NPTS = 16384;
constexpr int NQ   = 16384;
constexpr int QB   = 64;    // queries (rows) per block
constexpr int TPB  = 256;   // threads per block
constexpr int VEC  = 8;     // consecutive points per thread per iteration
constexpr int ITERS = NPTS / (TPB * VEC); // 8

__device__ __forceinline__ float norm2(float x, float y, float z) {
    return __fmaf_rn(x, x, __fmaf_rn(y, y, __fmul_rn(z, z)));
}

// squared distance, FMA-contracted, clamped at 0 (matches R5-R8 numerics)
__device__ __forceinline__ float sqdist(float qx, float qy, float qz, float q2,
                                        float dx, float dy, float dz, float d2) {
    const float dot = __fmaf_rn(qx, dx, __fmaf_rn(qy, dy, __fmul_rn(qz, dz)));
    const float s   = __fmaf_rn(-2.0f, dot, __fadd_rn(q2, d2));
    return fmaxf(s, 0.0f);
}

__global__ __launch_bounds__(TPB) void ball_kernel(
    const float* __restrict__ data,      // [N,3]
    const float* __restrict__ queries,   // [Q,3]
    const float* __restrict__ radius_p,  // [1]
    float* __restrict__ out,
    int* __restrict__ counts)            // [Q] in workspace
{
    const int tid  = threadIdx.x;
    const int lane = tid & 63;
    const int q0   = blockIdx.x * QB;

    __shared__ float qs[(QB + 1) * 3];   // queries q0-1 .. q0+QB-1
    __shared__ int   scnt[QB];
    if (tid < (QB + 1) * 3) {
        int src = q0 * 3 - 3 + tid;
        if (src < 0) src = 0;            // block 0 dummy; its row-head slot lands on
                                         // row_splits[Q], overwritten by scan after.
        qs[tid] = queries[src];
    }
    if (tid < QB) scnt[tid] = 0;
    __syncthreads();

    const float r  = radius_p[0];
    const float r2 = __fmul_rn(r, r);

    // Last data point (row-head weights slots refer to prev row's last element).
    const float lxx = data[(size_t)(NPTS - 1) * 3 + 0];
    const float lyy = data[(size_t)(NPTS - 1) * 3 + 1];
    const float lzz = data[(size_t)(NPTS - 1) * 3 + 2];
    const float l2  = norm2(lxx, lyy, lzz);

    float* __restrict__ mask = out;
    float* __restrict__ wts  = out + ((size_t)NQ * NPTS + NQ + 1);

#pragma unroll 1
    for (int q = 0; q < QB; ++q) {
        const float qxq = qs[3 * (q + 1) + 0];
        const float qyq = qs[3 * (q + 1) + 1];
        const float qzq = qs[3 * (q + 1) + 2];
        const float q2q = norm2(qxq, qyq, qzq);

        // Row-head slot value: weight(query q0+q-1, point NPTS-1).
        const float px = qs[3 * q + 0], py = qs[3 * q + 1], pz = qs[3 * q + 2];
        const float sqh = sqdist(px, py, pz, norm2(px, py, pz), lxx, lyy, lzz, l2);
        const float wheadq = (sqh <= r2) ? sqh : 0.0f;

        float* __restrict__ mrow = mask + (size_t)(q0 + q) * NPTS;
        float* __restrict__ wrow = wts  + (size_t)(q0 + q) * NPTS;

        int cnt = 0;

        // ---- prefetch tile it=0 into registers ----
        const int nb0 = tid * VEC;
        const float* db0 = data + (size_t)nb0 * 3;
        float4 cA = *reinterpret_cast<const float4*>(db0 + 0);
        float4 cB = *reinterpret_cast<const float4*>(db0 + 4);
        float4 cC = *reinterpret_cast<const float4*>(db0 + 8);
        float4 cD = *reinterpret_cast<const float4*>(db0 + 12);
        float4 cE = *reinterpret_cast<const float4*>(db0 + 16);
        float4 cF = *reinterpret_cast<const float4*>(db0 + 20);
        const int pm10 = (nb0 == 0) ? 0 : nb0 - 1;
        float cmx = data[(size_t)pm10 * 3 + 0];
        float cmy = data[(size_t)pm10 * 3 + 1];
        float cmz = data[(size_t)pm10 * 3 + 2];

#pragma unroll 1
        for (int it = 0; it < ITERS; ++it) {
            const int nb = (it * TPB + tid) * VEC;

            // ---- issue prefetch for tile it+1 (ahead of this tile's stores, so
            //      vmcnt waits on these loads never drain the store queue) ----
            float4 nA, nB, nC, nD, nE, nF;
            float nmx, nmy, nmz;
            if (it + 1 < ITERS) {
                const int nbn = ((it + 1) * TPB + tid) * VEC;   // >= 2048, no clamp
                const float* dbn = data + (size_t)nbn * 3;
                nA = *reinterpret_cast<const float4*>(dbn + 0);
                nB = *reinterpret_cast<const float4*>(dbn + 4);
                nC = *reinterpret_cast<const float4*>(dbn + 8);
                nD = *reinterpret_cast<const float4*>(dbn + 12);
                nE = *reinterpret_cast<const float4*>(dbn + 16);
                nF = *reinterpret_cast<const float4*>(dbn + 20);
                nmx = data[(size_t)(nbn - 1) * 3 + 0];
                nmy = data[(size_t)(nbn - 1) * 3 + 1];
                nmz = data[(size_t)(nbn - 1) * 3 + 2];
            }

            // ---- compute from current registers ----
            const float dx[VEC] = {cA.x, cA.w, cB.z, cC.y, cD.x, cD.w, cE.z, cF.y};
            const float dy[VEC] = {cA.y, cB.x, cB.w, cC.z, cD.y, cE.x, cE.w, cF.z};
            const float dz[VEC] = {cA.z, cB.y, cC.x, cC.w, cD.z, cE.y, cF.x, cF.w};

            float m[VEC], w[VEC];
#pragma unroll
            for (int j = 0; j < VEC; ++j) {
                const float d2 = norm2(dx[j], dy[j], dz[j]);
                const float sq = sqdist(qxq, qyq, qzq, q2q, dx[j], dy[j], dz[j], d2);
                const bool in = (sq <= r2);
                m[j] = in ? 1.0f : 0.0f;
                w[j] = in ? sq : 0.0f;
                cnt += in ? 1 : 0;
            }

            // Quad slot 0 at row elem nb-1: previous lane's w[7] via shfl;
            // lane 0 recomputes point nb-1 directly (bit-identical formula).
            const float m2  = norm2(cmx, cmy, cmz);
            const float sqm = sqdist(qxq, qyq, qzq, q2q, cmx, cmy, cmz, m2);
            const float wprev = (sqm <= r2) ? sqm : 0.0f;
            const float wsh = __shfl_up(w[7], 1);
            float slot0 = (lane == 0) ? wprev : wsh;
            if (tid == 0 && it == 0) slot0 = wheadq;

            *reinterpret_cast<float4*>(mrow + nb) =
                make_float4(m[0], m[1], m[2], m[3]);
            *reinterpret_cast<float4*>(mrow + nb + 4) =
                make_float4(m[4], m[5], m[6], m[7]);
            *reinterpret_cast<float4*>(wrow + nb - 1) =
                make_float4(slot0, w[0], w[1], w[2]);
            *reinterpret_cast<float4*>(wrow + nb + 3) =
                make_float4(w[3], w[4], w[5], w[6]);
            // w[7] is the next thread's slot0 (or row-head / global-tail case).

            // ---- rotate prefetch registers ----
            if (it + 1 < ITERS) {
                cA = nA; cB = nB; cC = nC; cD = nD; cE = nE; cF = nF;
                cmx = nmx; cmy = nmy; cmz = nmz;
            }
        }

        // Reduce this row's count across the block.
        for (int off = 32; off >= 1; off >>= 1) cnt += __shfl_down(cnt, off);
        if (lane == 0) atomicAdd(&scnt[q], cnt);
    }

    // Very last weights element (row NQ-1, elem NPTS-1) has no quad owner.
    if (q0 == NQ - QB && tid == TPB - 1) {
        const float qxq = qs[3 * QB + 0];
        const float qyq = qs[3 * QB + 1];
        const float qzq = qs[3 * QB + 2];
        const float sq = sqdist(qxq, qyq, qzq, norm2(qxq, qyq, qzq),
                                lxx, lyy, lzz, l2);
        wts[(size_t)(NQ - 1) * NPTS + (NPTS - 1)] = (sq <= r2) ? sq : 0.0f;
    }

    __syncthreads();
    if (tid < QB) counts[q0 + tid] = scnt[tid];
}

constexpr int STPB  = 256;
constexpr int CHUNK = NQ / STPB; // 64

__global__ __launch_bounds__(STPB) void scan_kernel(
    const int* __restrict__ counts, float* __restrict__ out)
{
    __shared__ int sums[STPB];
    const int tid  = threadIdx.x;
    const int base = tid * CHUNK;

    int s = 0;
    for (int i = 0; i < CHUNK; ++i) s += counts[base + i];
    sums[tid] = s;
    __syncthreads();

    for (int off = 1; off < STPB; off <<= 1) {
        int v = 0;
        if (tid >= off) v = sums[tid - off];
        __syncthreads();
        sums[tid] += v;
        __syncthreads();
    }

    int run = (tid == 0) ? 0 : sums[tid - 1];
    float* rs = out + (size_t)NQ * NPTS;
    if (tid == 0) rs[0] = 0.0f;
    for (int i = 0; i < CHUNK; ++i) {
        run += counts[base + i];
        rs[base + i + 1] = (float)run;
    }
}

} // namespace

extern "C" void kernel_launch(void* const* d_in, const int* in_sizes, int n_in,
                              void* d_out, int out_size, void* d_ws, size_t ws_size,
                              hipStream_t stream) {
    const float* data    = (const float*)d_in[0];
    const float* queries = (const float*)d_in[1];
    const float* radius  = (const float*)d_in[2];
    float* out  = (float*)d_out;
    int* counts = (int*)d_ws;

    hipLaunchKernelGGL(ball_kernel, dim3(NQ / QB), dim3(TPB), 0, stream,
                       data, queries, radius, out, counts);
    hipLaunchKernelGGL(scan_kernel, dim3(1), dim3(STPB), 0, stream, counts, out);
}

// Round 10
// 407.998 us; speedup vs baseline: 1.0428x; 1.0428x over previous
//
#include <hip/hip_runtime.h>
#include <cstddef>

// N=Q=16384, D=3. d_out (flat f32): mask [Q*N] | row_splits [Q+1] | weights [Q*N].
// Weights region starts at abs elem ≡ 1 (mod 4); aligned weights quads cover row
// elems {4k-1..4k+2}. Quad slot 0 = left neighbor's value: shfl_up across lanes,
// direct recompute at lane 0, prev-row tail at row heads.
// Ladder: R4 all-dwordx4 stores (586->438); R6 q-loop outermost (->409.6);
// R7 block-split regressed (993); R8 register prefetch (409.3, best);
// R9 QB=64/1-block-per-CU regressed (425). FINAL = R8 config.
// Practical ceiling: 2.147 GB writes @ ~5.45 TB/s effective (86% of the 6.33
// TB/s fill-rate on this buffer); read+dual-write mixing costs the rest.

namespace {

constexpr int NPTS = 16384;
constexpr int NQ   = 16384;
constexpr int QB   = 8;     // queries (rows) per block
constexpr int TPB  = 256;   // threads per block
constexpr int VEC  = 8;     // consecutive points per thread per iteration
constexpr int ITERS = NPTS / (TPB * VEC); // 8

__device__ __forceinline__ float norm2(float x, float y, float z) {
    return __fmaf_rn(x, x, __fmaf_rn(y, y, __fmul_rn(z, z)));
}

// squared distance, FMA-contracted, clamped at 0
__device__ __forceinline__ float sqdist(float qx, float qy, float qz, float q2,
                                        float dx, float dy, float dz, float d2) {
    const float dot = __fmaf_rn(qx, dx, __fmaf_rn(qy, dy, __fmul_rn(qz, dz)));
    const float s   = __fmaf_rn(-2.0f, dot, __fadd_rn(q2, d2));
    return fmaxf(s, 0.0f);
}

__global__ __launch_bounds__(TPB) void ball_kernel(
    const float* __restrict__ data,      // [N,3]
    const float* __restrict__ queries,   // [Q,3]
    const float* __restrict__ radius_p,  // [1]
    float* __restrict__ out,
    int* __restrict__ counts)            // [Q] in workspace
{
    const int tid  = threadIdx.x;
    const int lane = tid & 63;
    const int q0   = blockIdx.x * QB;

    __shared__ float qs[(QB + 1) * 3];   // queries q0-1 .. q0+QB-1
    __shared__ int   scnt[QB];
    if (tid < (QB + 1) * 3) {
        int src = q0 * 3 - 3 + tid;
        if (src < 0) src = 0;            // block 0 dummy; its row-head slot lands on
                                         // row_splits[Q], overwritten by scan after.
        qs[tid] = queries[src];
    }
    if (tid < QB) scnt[tid] = 0;
    __syncthreads();

    const float r  = radius_p[0];
    const float r2 = __fmul_rn(r, r);

    // Last data point (row-head weights slots refer to prev row's last element).
    const float lxx = data[(size_t)(NPTS - 1) * 3 + 0];
    const float lyy = data[(size_t)(NPTS - 1) * 3 + 1];
    const float lzz = data[(size_t)(NPTS - 1) * 3 + 2];
    const float l2  = norm2(lxx, lyy, lzz);

    float* __restrict__ mask = out;
    float* __restrict__ wts  = out + ((size_t)NQ * NPTS + NQ + 1);

#pragma unroll 1
    for (int q = 0; q < QB; ++q) {
        const float qxq = qs[3 * (q + 1) + 0];
        const float qyq = qs[3 * (q + 1) + 1];
        const float qzq = qs[3 * (q + 1) + 2];
        const float q2q = norm2(qxq, qyq, qzq);

        // Row-head slot value: weight(query q0+q-1, point NPTS-1).
        const float px = qs[3 * q + 0], py = qs[3 * q + 1], pz = qs[3 * q + 2];
        const float sqh = sqdist(px, py, pz, norm2(px, py, pz), lxx, lyy, lzz, l2);
        const float wheadq = (sqh <= r2) ? sqh : 0.0f;

        float* __restrict__ mrow = mask + (size_t)(q0 + q) * NPTS;
        float* __restrict__ wrow = wts  + (size_t)(q0 + q) * NPTS;

        int cnt = 0;

        // ---- prefetch tile it=0 into registers ----
        const int nb0 = tid * VEC;
        const float* db0 = data + (size_t)nb0 * 3;
        float4 cA = *reinterpret_cast<const float4*>(db0 + 0);
        float4 cB = *reinterpret_cast<const float4*>(db0 + 4);
        float4 cC = *reinterpret_cast<const float4*>(db0 + 8);
        float4 cD = *reinterpret_cast<const float4*>(db0 + 12);
        float4 cE = *reinterpret_cast<const float4*>(db0 + 16);
        float4 cF = *reinterpret_cast<const float4*>(db0 + 20);
        const int pm10 = (nb0 == 0) ? 0 : nb0 - 1;
        float cmx = data[(size_t)pm10 * 3 + 0];
        float cmy = data[(size_t)pm10 * 3 + 1];
        float cmz = data[(size_t)pm10 * 3 + 2];

#pragma unroll 1
        for (int it = 0; it < ITERS; ++it) {
            const int nb = (it * TPB + tid) * VEC;

            // ---- issue prefetch for tile it+1 (ahead of this tile's stores) ----
            float4 nA, nB, nC, nD, nE, nF;
            float nmx, nmy, nmz;
            if (it + 1 < ITERS) {
                const int nbn = ((it + 1) * TPB + tid) * VEC;   // >= 2048, no clamp
                const float* dbn = data + (size_t)nbn * 3;
                nA = *reinterpret_cast<const float4*>(dbn + 0);
                nB = *reinterpret_cast<const float4*>(dbn + 4);
                nC = *reinterpret_cast<const float4*>(dbn + 8);
                nD = *reinterpret_cast<const float4*>(dbn + 12);
                nE = *reinterpret_cast<const float4*>(dbn + 16);
                nF = *reinterpret_cast<const float4*>(dbn + 20);
                nmx = data[(size_t)(nbn - 1) * 3 + 0];
                nmy = data[(size_t)(nbn - 1) * 3 + 1];
                nmz = data[(size_t)(nbn - 1) * 3 + 2];
            }

            // ---- compute from current registers ----
            const float dx[VEC] = {cA.x, cA.w, cB.z, cC.y, cD.x, cD.w, cE.z, cF.y};
            const float dy[VEC] = {cA.y, cB.x, cB.w, cC.z, cD.y, cE.x, cE.w, cF.z};
            const float dz[VEC] = {cA.z, cB.y, cC.x, cC.w, cD.z, cE.y, cF.x, cF.w};

            float m[VEC], w[VEC];
#pragma unroll
            for (int j = 0; j < VEC; ++j) {
                const float d2 = norm2(dx[j], dy[j], dz[j]);
                const float sq = sqdist(qxq, qyq, qzq, q2q, dx[j], dy[j], dz[j], d2);
                const bool in = (sq <= r2);
                m[j] = in ? 1.0f : 0.0f;
                w[j] = in ? sq : 0.0f;
                cnt += in ? 1 : 0;
            }

            // Quad slot 0 at row elem nb-1: previous lane's w[7] via shfl;
            // lane 0 recomputes point nb-1 directly (bit-identical formula).
            const float m2  = norm2(cmx, cmy, cmz);
            const float sqm = sqdist(qxq, qyq, qzq, q2q, cmx, cmy, cmz, m2);
            const float wprev = (sqm <= r2) ? sqm : 0.0f;
            const float wsh = __shfl_up(w[7], 1);
            float slot0 = (lane == 0) ? wprev : wsh;
            if (tid == 0 && it == 0) slot0 = wheadq;

            *reinterpret_cast<float4*>(mrow + nb) =
                make_float4(m[0], m[1], m[2], m[3]);
            *reinterpret_cast<float4*>(mrow + nb + 4) =
                make_float4(m[4], m[5], m[6], m[7]);
            *reinterpret_cast<float4*>(wrow + nb - 1) =
                make_float4(slot0, w[0], w[1], w[2]);
            *reinterpret_cast<float4*>(wrow + nb + 3) =
                make_float4(w[3], w[4], w[5], w[6]);
            // w[7] is the next thread's slot0 (or row-head / global-tail case).

            // ---- rotate prefetch registers ----
            if (it + 1 < ITERS) {
                cA = nA; cB = nB; cC = nC; cD = nD; cE = nE; cF = nF;
                cmx = nmx; cmy = nmy; cmz = nmz;
            }
        }

        // Reduce this row's count across the block.
        for (int off = 32; off >= 1; off >>= 1) cnt += __shfl_down(cnt, off);
        if (lane == 0) atomicAdd(&scnt[q], cnt);
    }

    // Very last weights element (row NQ-1, elem NPTS-1) has no quad owner.
    if (q0 == NQ - QB && tid == TPB - 1) {
        const float qxq = qs[3 * QB + 0];
        const float qyq = qs[3 * QB + 1];
        const float qzq = qs[3 * QB + 2];
        const float sq = sqdist(qxq, qyq, qzq, norm2(qxq, qyq, qzq),
                                lxx, lyy, lzz, l2);
        wts[(size_t)(NQ - 1) * NPTS + (NPTS - 1)] = (sq <= r2) ? sq : 0.0f;
    }

    __syncthreads();
    if (tid < QB) counts[q0 + tid] = scnt[tid];
}

constexpr int STPB  = 256;
constexpr int CHUNK = NQ / STPB; // 64

__global__ __launch_bounds__(STPB) void scan_kernel(
    const int* __restrict__ counts, float* __restrict__ out)
{
    __shared__ int sums[STPB];
    const int tid  = threadIdx.x;
    const int base = tid * CHUNK;

    int s = 0;
    for (int i = 0; i < CHUNK; ++i) s += counts[base + i];
    sums[tid] = s;
    __syncthreads();

    for (int off = 1; off < STPB; off <<= 1) {
        int v = 0;
        if (tid >= off) v = sums[tid - off];
        __syncthreads();
        sums[tid] += v;
        __syncthreads();
    }

    int run = (tid == 0) ? 0 : sums[tid - 1];
    float* rs = out + (size_t)NQ * NPTS;
    if (tid == 0) rs[0] = 0.0f;
    for (int i = 0; i < CHUNK; ++i) {
        run += counts[base + i];
        rs[base + i + 1] = (float)run;
    }
}

} // namespace

extern "C" void kernel_launch(void* const* d_in, const int* in_sizes, int n_in,
                              void* d_out, int out_size, void* d_ws, size_t ws_size,
                              hipStream_t stream) {
    const float* data    = (const float*)d_in[0];
    const float* queries = (const float*)d_in[1];
    const float* radius  = (const float*)d_in[2];
    float* out  = (float*)d_out;
    int* counts = (int*)d_ws;

    hipLaunchKernelGGL(ball_kernel, dim3(NQ / QB), dim3(TPB), 0, stream,
                       data, queries, radius, out, counts);
    hipLaunchKernelGGL(scan_kernel, dim3(1), dim3(STPB), 0, stream, counts, out);
}